// Round 1
// baseline (150.034 us; speedup 1.0000x reference)
//
#include <hip/hip_runtime.h>
#include <math.h>

// Problem constants
#define BATCH 8192
#define LOD 60
#define LSD 120
#define AD 10
#define NB 15
#define BW 3
#define H 60

// Output layout (floats)
#define NM_SZ (BATCH * LSD)   // next_mean 983040
#define NC_SZ (BATCH * LOD)   // 491520 each for ncu/ncl/ncs

// Workspace layout (floats)
#define WS_COEF 0                        // [NB][BATCH] transposed coef
#define WS_CTRL (NB * BATCH)             // [LSD][BATCH] transposed control
#define WS_TMBG (NB * BATCH + LSD * BATCH) // [LOD][NB][8 float4] banded tm pack
// tmbg element (i,k,jo,m) at (i*NB + k)*32 + jo*4 + m ; jo in [0,7), zero-filled OOB

__device__ __forceinline__ float elup1f(float x) {
    return x < 0.0f ? __expf(x) : x + 1.0f;
}

// ---------------------------------------------------------------------------
// Kernel 1: blocks [0,512): coef (softmax over 15) + control MLP, transposed
//           blocks [512,611): banded tm transpose/pack into tmbg
// ---------------------------------------------------------------------------
__global__ __launch_bounds__(256) void k1_coef_ctrl_pack(
    const float* __restrict__ pm, const float* __restrict__ action,
    const float* __restrict__ tm11, const float* __restrict__ tm12,
    const float* __restrict__ tm21, const float* __restrict__ tm22,
    const float* __restrict__ w_coef, const float* __restrict__ b_coef,
    const float* __restrict__ w_c1, const float* __restrict__ b_c1,
    const float* __restrict__ w_c2, const float* __restrict__ b_c2,
    float* __restrict__ coef_t, float* __restrict__ ctrl_t,
    float* __restrict__ tmbg)
{
    const int tid = threadIdx.x;
    if (blockIdx.x >= 512) {
        // --- banded tm pack: 60*15*7*4 = 25200 elements ---
        int idx = (blockIdx.x - 512) * 256 + tid;
        if (idx < LOD * NB * 7 * 4) {
            int i  = idx / (NB * 28);
            int r  = idx % (NB * 28);
            int k  = r / 28;
            int r2 = r % 28;
            int jo = r2 >> 2;
            int m  = r2 & 3;
            int j  = i - BW + jo;
            const float* tmm = (m == 0) ? tm11 : (m == 1) ? tm12 : (m == 2) ? tm21 : tm22;
            float val = (j >= 0 && j < LOD) ? tmm[k * (LOD * LOD) + i * LOD + j] : 0.0f;
            tmbg[(i * NB + k) * 32 + jo * 4 + m] = val;
        }
        return;
    }

    // --- 16 batches per block, 16 threads per batch ---
    __shared__ float pm_s[16 * LSD];     // 1920
    __shared__ float act_s[16 * AD];     // 160
    __shared__ float lg_s[16 * 16];      // logits
    __shared__ float hid_s[16 * 64];     // hidden (padded 60->64)

    const int b0 = blockIdx.x * 16;

    for (int idx = tid; idx < 16 * LSD; idx += 256) pm_s[idx] = pm[b0 * LSD + idx];
    for (int idx = tid; idx < 16 * AD; idx += 256)  act_s[idx] = action[b0 * AD + idx];
    __syncthreads();

    const int bl = tid >> 4;
    const int q  = tid & 15;
    const int bglob = b0 + bl;

    // logits: q < 15 computes logit q for batch bl
    if (q < NB) {
        const float4* pmv = (const float4*)(pm_s + bl * LSD);
        const float4* wv  = (const float4*)(w_coef + q * LSD);
        float acc = b_coef[q];
        #pragma unroll
        for (int d = 0; d < LSD / 4; ++d) {
            float4 a = pmv[d];
            float4 w = wv[d];
            acc = fmaf(a.x, w.x, acc);
            acc = fmaf(a.y, w.y, acc);
            acc = fmaf(a.z, w.z, acc);
            acc = fmaf(a.w, w.w, acc);
        }
        lg_s[bl * 16 + q] = acc;
    }
    __syncthreads();

    if (q < NB) {
        float mx = lg_s[bl * 16 + 0];
        #pragma unroll
        for (int jj = 1; jj < NB; ++jj) mx = fmaxf(mx, lg_s[bl * 16 + jj]);
        float sm = 0.0f;
        #pragma unroll
        for (int jj = 0; jj < NB; ++jj) sm += __expf(lg_s[bl * 16 + jj] - mx);
        float ex = __expf(lg_s[bl * 16 + q] - mx);
        coef_t[q * BATCH + bglob] = ex / sm;
    }

    // hidden layer: h = q + r*16
    #pragma unroll
    for (int r = 0; r < 4; ++r) {
        int h = q + r * 16;
        if (h < H) {
            float acc = b_c1[h];
            #pragma unroll
            for (int a = 0; a < AD; ++a)
                acc = fmaf(act_s[bl * AD + a], w_c1[h * AD + a], acc);
            hid_s[bl * 64 + h] = fmaxf(acc, 0.0f);
        }
    }
    __syncthreads();

    // output layer: o = q + r*16
    #pragma unroll
    for (int r = 0; r < 8; ++r) {
        int o = q + r * 16;
        if (o < LSD) {
            const float4* hv = (const float4*)(hid_s + bl * 64);
            const float4* wv = (const float4*)(w_c2 + o * H);
            float acc = b_c2[o];
            #pragma unroll
            for (int hh = 0; hh < H / 4; ++hh) {
                float4 a = hv[hh];
                float4 w = wv[hh];
                acc = fmaf(a.x, w.x, acc);
                acc = fmaf(a.y, w.y, acc);
                acc = fmaf(a.z, w.z, acc);
                acc = fmaf(a.w, w.w, acc);
            }
            ctrl_t[o * BATCH + bglob] = acc;
        }
    }
}

// ---------------------------------------------------------------------------
// Kernel 2: main banded predict.
// Grid: 128 batch-groups x 5 row-groups. Block: 256 thr = 4 waves.
// lane <-> batch (64), wave w handles rows i0+3w .. i0+3w+2.
// ---------------------------------------------------------------------------
__global__ __launch_bounds__(256, 4) void k2_predict(
    const float* __restrict__ pm, const float* __restrict__ cu,
    const float* __restrict__ cl, const float* __restrict__ cs,
    const float* __restrict__ log_noise,
    const float* __restrict__ coef_t, const float* __restrict__ ctrl_t,
    const float* __restrict__ tmbg,
    float* __restrict__ out)
{
    const int tid  = threadIdx.x;
    const int wave = tid >> 6;
    const int lane = tid & 63;

    const int bg = blockIdx.x / 5;   // batch group
    const int rg = blockIdx.x % 5;   // row group
    const int b0 = bg * 64;
    const int i0 = rg * 12;
    const int b  = b0 + lane;

    // staged input vectors, transposed: [v][jj][bl], jj = j - (i0-3), 18 wide
    __shared__ float vs[5 * 18 * 64];       // 23040 B
    // staged outputs: [o][ri][bl], padded stride 65 to break bank conflicts
    __shared__ float ost[5 * 12 * 65];      // 15600 B

    for (int idx = tid; idx < 5 * 18 * 64; idx += 256) {
        int v   = idx / (18 * 64);
        int rem = idx - v * (18 * 64);
        int jj  = rem >> 6;
        int blc = rem & 63;
        int j   = i0 - BW + jj;
        int bb  = b0 + blc;
        float val = 0.0f;
        if (j >= 0 && j < LOD) {
            if (v == 0)      val = pm[bb * LSD + j];
            else if (v == 1) val = pm[bb * LSD + LOD + j];
            else if (v == 2) val = cu[bb * LOD + j];
            else if (v == 3) val = cl[bb * LOD + j];
            else             val = cs[bb * LOD + j];
        }
        vs[idx] = val;
    }

    // per-lane coef (independent of LDS)
    float cf[NB];
    #pragma unroll
    for (int k = 0; k < NB; ++k) cf[k] = coef_t[k * BATCH + b];

    __syncthreads();

    #pragma unroll
    for (int rr = 0; rr < 3; ++rr) {
        const int ri = wave * 3 + rr;
        const int i  = i0 + ri;
        const int iu = __builtin_amdgcn_readfirstlane(i);  // wave-uniform row

        // ---- mixing: t[jo*4+m] = sum_k cf[k] * tmbg[i][k][jo][m] ----
        float t[28];
        #pragma unroll
        for (int z = 0; z < 28; ++z) t[z] = 0.0f;

        const float4* tp = (const float4*)tmbg + (size_t)iu * (NB * 8);
        #pragma unroll
        for (int k = 0; k < NB; ++k) {
            float c = cf[k];
            #pragma unroll
            for (int jo = 0; jo < 7; ++jo) {
                float4 tv = tp[k * 8 + jo];
                t[jo * 4 + 0] = fmaf(c, tv.x, t[jo * 4 + 0]);
                t[jo * 4 + 1] = fmaf(c, tv.y, t[jo * 4 + 1]);
                t[jo * 4 + 2] = fmaf(c, tv.z, t[jo * 4 + 2]);
                t[jo * 4 + 3] = fmaf(c, tv.w, t[jo * 4 + 3]);
            }
        }
        // + eye on t11 and t22 at j == i (jo == 3)
        t[3 * 4 + 0] += 1.0f;
        t[3 * 4 + 3] += 1.0f;

        // ---- banded products ----
        float nmu = 0.f, nml = 0.f, ncuv = 0.f, nclv = 0.f, ncsv = 0.f;
        #pragma unroll
        for (int jo = 0; jo < 7; ++jo) {
            const int jj = ri + jo;
            float m_ = vs[0 * 1152 + jj * 64 + lane];
            float n_ = vs[1 * 1152 + jj * 64 + lane];
            float u_ = vs[2 * 1152 + jj * 64 + lane];
            float l_ = vs[3 * 1152 + jj * 64 + lane];
            float s_ = vs[4 * 1152 + jj * 64 + lane];
            float A = t[jo * 4 + 0], Bv = t[jo * 4 + 1];
            float C = t[jo * 4 + 2], D  = t[jo * 4 + 3];
            nmu = fmaf(A, m_, nmu);  nmu = fmaf(Bv, n_, nmu);
            nml = fmaf(C, m_, nml);  nml = fmaf(D, n_, nml);
            float e1 = fmaf(Bv, s_, A * u_);   // A*u + B*s
            float e2 = fmaf(Bv, l_, A * s_);   // A*s + B*l
            float f1 = fmaf(D, s_, C * u_);    // C*u + D*s
            float f2 = fmaf(D, l_, C * s_);    // C*s + D*l
            ncuv = fmaf(A, e1, ncuv);  ncuv = fmaf(Bv, e2, ncuv);
            nclv = fmaf(C, f1, nclv);  nclv = fmaf(D, f2, nclv);
            ncsv = fmaf(C, e1, ncsv);  ncsv = fmaf(D, e2, ncsv);
        }

        // trans_cov + control
        ncuv += elup1f(log_noise[iu]);
        nclv += elup1f(log_noise[LOD + iu]);
        nmu  += ctrl_t[iu * BATCH + b];
        nml  += ctrl_t[(LOD + iu) * BATCH + b];

        ost[0 * 780 + ri * 65 + lane] = nmu;
        ost[1 * 780 + ri * 65 + lane] = nml;
        ost[2 * 780 + ri * 65 + lane] = ncuv;
        ost[3 * 780 + ri * 65 + lane] = nclv;
        ost[4 * 780 + ri * 65 + lane] = ncsv;
    }
    __syncthreads();

    // coalesced-ish output write: idx over (bl, ri)
    for (int idx = tid; idx < 64 * 12; idx += 256) {
        int blc = idx / 12;
        int ri  = idx % 12;
        int bb  = b0 + blc;
        int i   = i0 + ri;
        out[bb * LSD + i]                    = ost[0 * 780 + ri * 65 + blc];
        out[bb * LSD + LOD + i]              = ost[1 * 780 + ri * 65 + blc];
        out[NM_SZ + bb * LOD + i]            = ost[2 * 780 + ri * 65 + blc];
        out[NM_SZ + NC_SZ + bb * LOD + i]    = ost[3 * 780 + ri * 65 + blc];
        out[NM_SZ + 2 * NC_SZ + bb * LOD + i] = ost[4 * 780 + ri * 65 + blc];
    }
}

extern "C" void kernel_launch(void* const* d_in, const int* in_sizes, int n_in,
                              void* d_out, int out_size, void* d_ws, size_t ws_size,
                              hipStream_t stream) {
    (void)in_sizes; (void)n_in; (void)out_size; (void)ws_size;
    const float* pm        = (const float*)d_in[0];
    const float* cu        = (const float*)d_in[1];
    const float* cl        = (const float*)d_in[2];
    const float* cs        = (const float*)d_in[3];
    const float* action    = (const float*)d_in[4];
    const float* tm11      = (const float*)d_in[5];
    const float* tm12      = (const float*)d_in[6];
    const float* tm21      = (const float*)d_in[7];
    const float* tm22      = (const float*)d_in[8];
    const float* log_noise = (const float*)d_in[9];
    const float* w_coef    = (const float*)d_in[10];
    const float* b_coef    = (const float*)d_in[11];
    const float* w_c1      = (const float*)d_in[12];
    const float* b_c1      = (const float*)d_in[13];
    const float* w_c2      = (const float*)d_in[14];
    const float* b_c2      = (const float*)d_in[15];

    float* ws     = (float*)d_ws;   // needs ~4.6 MB
    float* coef_t = ws + WS_COEF;
    float* ctrl_t = ws + WS_CTRL;
    float* tmbg   = ws + WS_TMBG;

    hipLaunchKernelGGL(k1_coef_ctrl_pack, dim3(611), dim3(256), 0, stream,
                       pm, action, tm11, tm12, tm21, tm22,
                       w_coef, b_coef, w_c1, b_c1, w_c2, b_c2,
                       coef_t, ctrl_t, tmbg);

    hipLaunchKernelGGL(k2_predict, dim3(128 * 5), dim3(256), 0, stream,
                       pm, cu, cl, cs, log_noise, coef_t, ctrl_t, tmbg,
                       (float*)d_out);
}

// Round 2
// 149.428 us; speedup vs baseline: 1.0041x; 1.0041x over previous
//
#include <hip/hip_runtime.h>
#include <math.h>

// Problem constants
#define BATCH 8192
#define LOD 60
#define LSD 120
#define AD 10
#define NB 15
#define BW 3
#define H 60

// Output layout (floats)
#define NM_SZ (BATCH * LSD)   // next_mean 983040
#define NC_SZ (BATCH * LOD)   // 491520 each for ncu/ncl/ncs

// Workspace layout (floats)
#define WS_COEF 0                          // [NB][BATCH] transposed coef
#define WS_CTRL (NB * BATCH)               // [LSD][BATCH] transposed control
#define WS_TMBG (NB * BATCH + LSD * BATCH) // [LOD][NB][8 float4] banded tm pack
// tmbg element (i,k,jo,m) at (i*NB + k)*32 + jo*4 + m ; jo in [0,7), zero-filled OOB

__device__ __forceinline__ float elup1f(float x) {
    return x < 0.0f ? __expf(x) : x + 1.0f;
}

// ---------------------------------------------------------------------------
// Kernel 1: blocks [0,512): coef (softmax over 15) + control MLP (16 batch/blk)
//           blocks [512,611): banded tm transpose/pack into tmbg
// All global writes staged in LDS and flushed batch-fastest (coalesced runs).
// ---------------------------------------------------------------------------
__global__ __launch_bounds__(256) void k1_coef_ctrl_pack(
    const float* __restrict__ pm, const float* __restrict__ action,
    const float* __restrict__ tm11, const float* __restrict__ tm12,
    const float* __restrict__ tm21, const float* __restrict__ tm22,
    const float* __restrict__ w_coef, const float* __restrict__ b_coef,
    const float* __restrict__ w_c1, const float* __restrict__ b_c1,
    const float* __restrict__ w_c2, const float* __restrict__ b_c2,
    float* __restrict__ coef_t, float* __restrict__ ctrl_t,
    float* __restrict__ tmbg)
{
    const int tid = threadIdx.x;
    if (blockIdx.x >= 512) {
        // --- banded tm pack: 60*15*7*4 = 25200 elements ---
        int idx = (blockIdx.x - 512) * 256 + tid;
        if (idx < LOD * NB * 7 * 4) {
            int i  = idx / (NB * 28);
            int r  = idx % (NB * 28);
            int k  = r / 28;
            int r2 = r % 28;
            int jo = r2 >> 2;
            int m  = r2 & 3;
            int j  = i - BW + jo;
            const float* tmm = (m == 0) ? tm11 : (m == 1) ? tm12 : (m == 2) ? tm21 : tm22;
            float val = (j >= 0 && j < LOD) ? tmm[k * (LOD * LOD) + i * LOD + j] : 0.0f;
            tmbg[(i * NB + k) * 32 + jo * 4 + m] = val;
        }
        return;
    }

    // --- 16 batches per block, 16 threads per batch ---
    __shared__ float pm_s[16 * LSD];      // [bl][j] contiguous (float4 dots)
    __shared__ float act_s[16 * AD];
    __shared__ float lg_s[16 * 16];       // [bl][k] logits
    __shared__ float coef_s[NB * 17];     // [k][b]  (transposed, padded)
    __shared__ float hid_s[16 * 64];      // [bl][h] contiguous (float4 dots)
    __shared__ float ctrl_s[LSD * 17];    // [o][b]  (transposed, padded)

    const int b0 = blockIdx.x * 16;

    for (int idx = tid; idx < 16 * LSD; idx += 256) pm_s[idx] = pm[b0 * LSD + idx];
    for (int idx = tid; idx < 16 * AD; idx += 256)  act_s[idx] = action[b0 * AD + idx];
    __syncthreads();

    const int bl = tid >> 4;
    const int q  = tid & 15;

    // logits: q < 15 computes logit q for batch bl
    if (q < NB) {
        const float4* pmv = (const float4*)(pm_s + bl * LSD);
        const float4* wv  = (const float4*)(w_coef + q * LSD);
        float acc = b_coef[q];
        #pragma unroll
        for (int d = 0; d < LSD / 4; ++d) {
            float4 a = pmv[d];
            float4 w = wv[d];
            acc = fmaf(a.x, w.x, acc);
            acc = fmaf(a.y, w.y, acc);
            acc = fmaf(a.z, w.z, acc);
            acc = fmaf(a.w, w.w, acc);
        }
        lg_s[bl * 16 + q] = acc;
    }
    __syncthreads();

    if (q < NB) {
        float mx = lg_s[bl * 16 + 0];
        #pragma unroll
        for (int jj = 1; jj < NB; ++jj) mx = fmaxf(mx, lg_s[bl * 16 + jj]);
        float sm = 0.0f;
        #pragma unroll
        for (int jj = 0; jj < NB; ++jj) sm += __expf(lg_s[bl * 16 + jj] - mx);
        float ex = __expf(lg_s[bl * 16 + q] - mx);
        coef_s[q * 17 + bl] = ex / sm;
    }

    // hidden layer: h = q + r*16
    #pragma unroll
    for (int r = 0; r < 4; ++r) {
        int h = q + r * 16;
        if (h < H) {
            float acc = b_c1[h];
            #pragma unroll
            for (int a = 0; a < AD; ++a)
                acc = fmaf(act_s[bl * AD + a], w_c1[h * AD + a], acc);
            hid_s[bl * 64 + h] = fmaxf(acc, 0.0f);
        }
    }
    __syncthreads();

    // output layer: o = q + r*16, staged transposed into ctrl_s
    #pragma unroll
    for (int r = 0; r < 8; ++r) {
        int o = q + r * 16;
        const float4* hv = (const float4*)(hid_s + bl * 64);
        const float4* wv = (const float4*)(w_c2 + o * H);
        float acc = b_c2[o];
        #pragma unroll
        for (int hh = 0; hh < H / 4; ++hh) {
            float4 a = hv[hh];
            float4 w = wv[hh];
            acc = fmaf(a.x, w.x, acc);
            acc = fmaf(a.y, w.y, acc);
            acc = fmaf(a.z, w.z, acc);
            acc = fmaf(a.w, w.w, acc);
        }
        ctrl_s[o * 17 + bl] = acc;
    }
    __syncthreads();

    // coalesced flushes: batch index fastest -> 64B contiguous runs
    if (tid < NB * 16) {
        int k = tid >> 4, b = tid & 15;
        coef_t[k * BATCH + b0 + b] = coef_s[k * 17 + b];
    }
    for (int idx = tid; idx < LSD * 16; idx += 256) {
        int o = idx >> 4, b = idx & 15;
        ctrl_t[o * BATCH + b0 + b] = ctrl_s[o * 17 + b];
    }
}

// ---------------------------------------------------------------------------
// Kernel 2: main banded predict.
// Grid: 128 batch-groups x 5 row-groups. Block: 256 thr = 4 waves.
// lane <-> batch (64), wave w handles rows i0+3w .. i0+3w+2.
// ---------------------------------------------------------------------------
#define VSJ 65
#define VSV (18 * VSJ)   // 1170 floats per tensor plane

__global__ __launch_bounds__(256) void k2_predict(
    const float* __restrict__ pm, const float* __restrict__ cu,
    const float* __restrict__ cl, const float* __restrict__ cs,
    const float* __restrict__ log_noise,
    const float* __restrict__ coef_t, const float* __restrict__ ctrl_t,
    const float* __restrict__ tmbg,
    float* __restrict__ out)
{
    const int tid  = threadIdx.x;
    const int wave = tid >> 6;
    const int lane = tid & 63;

    const int bg = blockIdx.x / 5;   // batch group
    const int rg = blockIdx.x % 5;   // row group
    const int b0 = bg * 64;
    const int i0 = rg * 12;
    const int b  = b0 + lane;

    // staged input vectors, transposed: [v][jj][blc], jj = j - (i0-3), stride 65
    __shared__ float vs[5 * VSV];           // 23.4 KB
    // staged outputs: [o][ri][blc], padded stride 65
    __shared__ float ost[5 * 12 * 65];      // 15.6 KB

    // coalesced staging: jj fastest -> 18-float (72B) contiguous global runs
    for (int idx = tid; idx < 5 * 64 * 18; idx += 256) {
        int v   = idx / (64 * 18);
        int rem = idx - v * (64 * 18);
        int blc = rem / 18;
        int jj  = rem - blc * 18;
        int j   = i0 - BW + jj;
        int bb  = b0 + blc;
        float val = 0.0f;
        if (j >= 0 && j < LOD) {
            if (v == 0)      val = pm[bb * LSD + j];
            else if (v == 1) val = pm[bb * LSD + LOD + j];
            else if (v == 2) val = cu[bb * LOD + j];
            else if (v == 3) val = cl[bb * LOD + j];
            else             val = cs[bb * LOD + j];
        }
        vs[v * VSV + jj * VSJ + blc] = val;
    }

    // per-lane coef (coalesced: lane = batch)
    float cf[NB];
    #pragma unroll
    for (int k = 0; k < NB; ++k) cf[k] = coef_t[k * BATCH + b];

    __syncthreads();

    #pragma unroll
    for (int rr = 0; rr < 3; ++rr) {
        const int ri = wave * 3 + rr;
        const int i  = i0 + ri;
        const int iu = __builtin_amdgcn_readfirstlane(i);  // wave-uniform row

        // ---- mixing: t[jo*4+m] = sum_k cf[k] * tmbg[i][k][jo][m] ----
        float t[28];
        #pragma unroll
        for (int z = 0; z < 28; ++z) t[z] = 0.0f;

        const float4* tp = (const float4*)tmbg + (size_t)iu * (NB * 8);
        #pragma unroll
        for (int k = 0; k < NB; ++k) {
            float c = cf[k];
            #pragma unroll
            for (int jo = 0; jo < 7; ++jo) {
                float4 tv = tp[k * 8 + jo];
                t[jo * 4 + 0] = fmaf(c, tv.x, t[jo * 4 + 0]);
                t[jo * 4 + 1] = fmaf(c, tv.y, t[jo * 4 + 1]);
                t[jo * 4 + 2] = fmaf(c, tv.z, t[jo * 4 + 2]);
                t[jo * 4 + 3] = fmaf(c, tv.w, t[jo * 4 + 3]);
            }
        }
        // + eye on t11 and t22 at j == i (jo == 3)
        t[3 * 4 + 0] += 1.0f;
        t[3 * 4 + 3] += 1.0f;

        // ---- banded products ----
        float nmu = 0.f, nml = 0.f, ncuv = 0.f, nclv = 0.f, ncsv = 0.f;
        #pragma unroll
        for (int jo = 0; jo < 7; ++jo) {
            const int jj = ri + jo;
            float m_ = vs[0 * VSV + jj * VSJ + lane];
            float n_ = vs[1 * VSV + jj * VSJ + lane];
            float u_ = vs[2 * VSV + jj * VSJ + lane];
            float l_ = vs[3 * VSV + jj * VSJ + lane];
            float s_ = vs[4 * VSV + jj * VSJ + lane];
            float A = t[jo * 4 + 0], Bv = t[jo * 4 + 1];
            float C = t[jo * 4 + 2], D  = t[jo * 4 + 3];
            nmu = fmaf(A, m_, nmu);  nmu = fmaf(Bv, n_, nmu);
            nml = fmaf(C, m_, nml);  nml = fmaf(D, n_, nml);
            float e1 = fmaf(Bv, s_, A * u_);   // A*u + B*s
            float e2 = fmaf(Bv, l_, A * s_);   // A*s + B*l
            float f1 = fmaf(D, s_, C * u_);    // C*u + D*s
            float f2 = fmaf(D, l_, C * s_);    // C*s + D*l
            ncuv = fmaf(A, e1, ncuv);  ncuv = fmaf(Bv, e2, ncuv);
            nclv = fmaf(C, f1, nclv);  nclv = fmaf(D, f2, nclv);
            ncsv = fmaf(C, e1, ncsv);  ncsv = fmaf(D, e2, ncsv);
        }

        // trans_cov + control
        ncuv += elup1f(log_noise[iu]);
        nclv += elup1f(log_noise[LOD + iu]);
        nmu  += ctrl_t[iu * BATCH + b];
        nml  += ctrl_t[(LOD + iu) * BATCH + b];

        ost[0 * 780 + ri * 65 + lane] = nmu;
        ost[1 * 780 + ri * 65 + lane] = nml;
        ost[2 * 780 + ri * 65 + lane] = ncuv;
        ost[3 * 780 + ri * 65 + lane] = nclv;
        ost[4 * 780 + ri * 65 + lane] = ncsv;
    }
    __syncthreads();

    // coalesced float4 output flush: each row-group writes 12 floats = 3 float4
    // per batch per tensor; all bases are 16B-aligned (i0 % 4 == 0).
    for (int idx = tid; idx < 5 * 64 * 3; idx += 256) {
        int t5  = idx / 192;
        int rem = idx - t5 * 192;
        int blc = rem / 3;
        int qq  = rem - blc * 3;
        int bb  = b0 + blc;
        int ri0 = qq * 4;
        float4 v;
        v.x = ost[t5 * 780 + (ri0 + 0) * 65 + blc];
        v.y = ost[t5 * 780 + (ri0 + 1) * 65 + blc];
        v.z = ost[t5 * 780 + (ri0 + 2) * 65 + blc];
        v.w = ost[t5 * 780 + (ri0 + 3) * 65 + blc];
        float* bp;
        if (t5 == 0)      bp = out + bb * LSD + i0;
        else if (t5 == 1) bp = out + bb * LSD + LOD + i0;
        else if (t5 == 2) bp = out + NM_SZ + bb * LOD + i0;
        else if (t5 == 3) bp = out + NM_SZ + NC_SZ + bb * LOD + i0;
        else              bp = out + NM_SZ + 2 * NC_SZ + bb * LOD + i0;
        *(float4*)(bp + ri0) = v;
    }
}

extern "C" void kernel_launch(void* const* d_in, const int* in_sizes, int n_in,
                              void* d_out, int out_size, void* d_ws, size_t ws_size,
                              hipStream_t stream) {
    (void)in_sizes; (void)n_in; (void)out_size; (void)ws_size;
    const float* pm        = (const float*)d_in[0];
    const float* cu        = (const float*)d_in[1];
    const float* cl        = (const float*)d_in[2];
    const float* cs        = (const float*)d_in[3];
    const float* action    = (const float*)d_in[4];
    const float* tm11      = (const float*)d_in[5];
    const float* tm12      = (const float*)d_in[6];
    const float* tm21      = (const float*)d_in[7];
    const float* tm22      = (const float*)d_in[8];
    const float* log_noise = (const float*)d_in[9];
    const float* w_coef    = (const float*)d_in[10];
    const float* b_coef    = (const float*)d_in[11];
    const float* w_c1      = (const float*)d_in[12];
    const float* b_c1      = (const float*)d_in[13];
    const float* w_c2      = (const float*)d_in[14];
    const float* b_c2      = (const float*)d_in[15];

    float* ws     = (float*)d_ws;   // needs ~1.5 MB
    float* coef_t = ws + WS_COEF;
    float* ctrl_t = ws + WS_CTRL;
    float* tmbg   = ws + WS_TMBG;

    hipLaunchKernelGGL(k1_coef_ctrl_pack, dim3(611), dim3(256), 0, stream,
                       pm, action, tm11, tm12, tm21, tm22,
                       w_coef, b_coef, w_c1, b_c1, w_c2, b_c2,
                       coef_t, ctrl_t, tmbg);

    hipLaunchKernelGGL(k2_predict, dim3(128 * 5), dim3(256), 0, stream,
                       pm, cu, cl, cs, log_noise, coef_t, ctrl_t, tmbg,
                       (float*)d_out);
}